// Round 5
// baseline (10469.858 us; speedup 1.0000x reference)
//
#include <hip/hip_runtime.h>

#define B_ 64
#define T_ 512
#define E_ 512
#define HD_ 256
#define H_ 512
#define K_ 16
#define NEG_ (-10000.0f)
#define START_ 13
#define STOP_ 14

typedef unsigned int u32;
using half8  = __attribute__((ext_vector_type(8))) _Float16;
using f32x4  = __attribute__((ext_vector_type(4))) float;
using half2v = __attribute__((ext_vector_type(2))) _Float16;

__device__ __forceinline__ int dot4i8(u32 a, u32 b, int c) {
#if __has_builtin(__builtin_amdgcn_sdot4)
    return __builtin_amdgcn_sdot4((int)a, (int)b, c, false);
#else
    int r = c;
#pragma unroll
    for (int i = 0; i < 4; ++i) {
        int xa = ((int)a << (24 - 8 * i)) >> 24;
        int xb = ((int)b << (24 - 8 * i)) >> 24;
        r += xa * xb;
    }
    return r;
#endif
}
__device__ __forceinline__ int dotq(uint4 w, uint4 h, int a) {
    a = dot4i8(w.x, h.x, a); a = dot4i8(w.y, h.y, a);
    a = dot4i8(w.z, h.z, a); a = dot4i8(w.w, h.w, a);
    return a;
}
__device__ __forceinline__ float sigm(float x) { return 1.f / (1.f + __expf(-x)); }
__device__ __forceinline__ float tanh_f(float x) {
    float a = fabsf(x);
    float e = __expf(-2.f * a);
    float t = (1.f - e) / (1.f + e);
    return x < 0.f ? -t : t;
}

// ---------------- converters ----------------
__global__ void cvt_f16_k(const float* __restrict__ src, _Float16* __restrict__ dst, int n4) {
    int i = blockIdx.x * blockDim.x + threadIdx.x;
    if (i < n4) {
        float4 v = ((const float4*)src)[i];
        half2v a; a.x = (_Float16)v.x; a.y = (_Float16)v.y;
        half2v b; b.x = (_Float16)v.z; b.y = (_Float16)v.w;
        ((u32*)dst)[2 * i]     = __builtin_bit_cast(u32, a);
        ((u32*)dst)[2 * i + 1] = __builtin_bit_cast(u32, b);
    }
}
__global__ void bias_sum_k(const float* __restrict__ bih, const float* __restrict__ bhh,
                           float* __restrict__ bs) {
    int i = blockIdx.x * blockDim.x + threadIdx.x;
    if (i < 4096) bs[i] = bih[i] + bhh[i];
}
__global__ void init_flags_k(u32* __restrict__ flags) {
    flags[threadIdx.x] = 0;   // 512 entries: [layer][pair][half]
}

// ---------------- W_hh row-scaled int8 quantization: one 64-thread block per row ------
__global__ void quant_whh_k(const float* __restrict__ whh,   // [4096][256]
                            u32* __restrict__ wq,            // [4096][64] packed i8
                            float* __restrict__ dqw) {       // [4096] dequant = rowmax/127^2
    const int row = blockIdx.x, lane = threadIdx.x;          // 64 lanes
    const float4 v = ((const float4*)(whh + (size_t)row * 256))[lane];
    float m = fmaxf(fmaxf(fabsf(v.x), fabsf(v.y)), fmaxf(fabsf(v.z), fabsf(v.w)));
#pragma unroll
    for (int off = 32; off >= 1; off >>= 1) m = fmaxf(m, __shfl_xor(m, off, 64));
    m = fmaxf(m, 1e-8f);
    const float s = 127.f / m;
    int b0 = ((int)rintf(v.x * s)) & 255;
    int b1 = ((int)rintf(v.y * s)) & 255;
    int b2 = ((int)rintf(v.z * s)) & 255;
    int b3 = ((int)rintf(v.w * s)) & 255;
    wq[(size_t)row * 64 + lane] = (u32)(b0 | (b1 << 8) | (b2 << 16) | (b3 << 24));
    if (lane == 0) dqw[row] = m / (127.f * 127.f);
}

// ---------------- embedding gather + cast to f16 ----------------
__global__ void embed_k(const int* __restrict__ x, const float* __restrict__ emb,
                        _Float16* __restrict__ xe) {
    int m = blockIdx.x;                  // 0..32767 = b*T + t
    int row = x[m];
    int c = threadIdx.x * 4;             // 128 threads * 4 = 512
    float4 v = *(const float4*)(emb + (size_t)row * E_ + c);
    half2v p0; p0.x = (_Float16)v.x; p0.y = (_Float16)v.y;
    half2v p1; p1.x = (_Float16)v.z; p1.y = (_Float16)v.w;
    u32* dst = (u32*)(xe + (size_t)m * E_) + threadIdx.x * 2;
    dst[0] = __builtin_bit_cast(u32, p0);
    dst[1] = __builtin_bit_cast(u32, p1);
}

// ---------------- f16 MFMA GEMM:  C[m,n] = sum_k A[m,k]*Bw[n,k] + bias[n]  (C f16) -----
__global__ __launch_bounds__(256) void gemm_bt(const _Float16* __restrict__ A,
                                               const _Float16* __restrict__ Bw,
                                               const float* __restrict__ bsum,
                                               _Float16* __restrict__ C,
                                               int M, int N, int Kd) {
    __shared__ __align__(16) _Float16 As[128 * 64];
    __shared__ __align__(16) _Float16 Bs[128 * 64];
    const int nTn = N >> 7;
    const int tm = blockIdx.x / nTn, tn = blockIdx.x % nTn;
    const int tid = threadIdx.x;
    const int lane = tid & 63, wave = tid >> 6;
    const int wr = wave >> 1, wc = wave & 1;      // 2x2 waves of 64x64
    f32x4 acc[4][4];
#pragma unroll
    for (int i = 0; i < 4; ++i)
#pragma unroll
        for (int j = 0; j < 4; ++j) acc[i][j] = f32x4{0.f, 0.f, 0.f, 0.f};
    const int lr = lane & 15, lk = (lane >> 4) * 8;

    for (int k0 = 0; k0 < Kd; k0 += 64) {
#pragma unroll
        for (int r = 0; r < 4; ++r) {
            int c = r * 256 + tid;                     // chunk id, 16B each
            const _Float16* srcA = A + (size_t)(tm * 128 + (c >> 3)) * Kd + k0 + (c & 7) * 8;
            const _Float16* srcB = Bw + (size_t)(tn * 128 + (c >> 3)) * Kd + k0 + (c & 7) * 8;
            _Float16* dA = &As[(size_t)(r * 256 + wave * 64) * 8];
            _Float16* dB = &Bs[(size_t)(r * 256 + wave * 64) * 8];
            __builtin_amdgcn_global_load_lds((const __attribute__((address_space(1))) void*)srcA,
                                             (__attribute__((address_space(3))) void*)dA, 16, 0, 0);
            __builtin_amdgcn_global_load_lds((const __attribute__((address_space(1))) void*)srcB,
                                             (__attribute__((address_space(3))) void*)dB, 16, 0, 0);
        }
        __syncthreads();
#pragma unroll
        for (int kk = 0; kk < 2; ++kk) {
            half8 av[4], bv[4];
#pragma unroll
            for (int i = 0; i < 4; ++i)
                av[i] = *(const half8*)&As[(wr * 64 + i * 16 + lr) * 64 + kk * 32 + lk];
#pragma unroll
            for (int j = 0; j < 4; ++j)
                bv[j] = *(const half8*)&Bs[(wc * 64 + j * 16 + lr) * 64 + kk * 32 + lk];
#pragma unroll
            for (int i = 0; i < 4; ++i)
#pragma unroll
                for (int j = 0; j < 4; ++j)
                    acc[i][j] = __builtin_amdgcn_mfma_f32_16x16x32_f16(av[i], bv[j], acc[i][j], 0, 0, 0);
        }
        __syncthreads();
    }
    const int mq = (lane >> 4) * 4;
#pragma unroll
    for (int i = 0; i < 4; ++i)
#pragma unroll
        for (int j = 0; j < 4; ++j) {
            int m0 = tm * 128 + wr * 64 + i * 16 + mq;
            int n0 = tn * 128 + wc * 64 + j * 16 + lr;
            float bv = bsum[n0];
#pragma unroll
            for (int q = 0; q < 4; ++q)
                C[(size_t)(m0 + q) * N + n0] = (_Float16)(acc[i][j][q] + bv);
        }
}

// ---------------- LSTM recurrence, PAIR-SPLIT across 2 CUs --------------------------
// 256 blocks: block = (pair p = b*2+dir, half hf). Each block computes 512 gate rows
// (units [hf*128, hf*128+128), gates i,f,g,o) and owns that half of c/h. The 256-unit
// h vector is exchanged per step via L2 (agent-scope atomics) with a release/acquire
// flag handshake; parity double-buffer, monotonic flags (safe: a block overwrites
// slot parity(s) only after partner's flag >= s+1, i.e. partner consumed slot s).
// Thread = (row r = g*128+ul, col-half ch): 32 sdot4; weights 24 u32 VGPR + 8 u32 LDS.
__global__ __launch_bounds__(1024) void lstm_pair_k(
    const u32* __restrict__ wq,           // [2][1024][64] packed i8 (this layer)
    const float* __restrict__ dqw,        // [2][1024] rowmax/127^2 (this layer)
    const float* __restrict__ h0,         // [2][64][256]
    const float* __restrict__ c0,         // [2][64][256]
    const _Float16* __restrict__ Z,       // [32768][2048] f16 preacts (x@Wih + bias)
    _Float16* __restrict__ Hout,          // [32768][512] f16
    u32* __restrict__ xh,                 // [128 pairs][2 hf][2 parity][32 u32]
    u32* __restrict__ flags) {            // [128 pairs][2 hf], zeroed per launch
    __shared__ __align__(16) uint4 wl[2][1024];      // 32 KB weight tails
    __shared__ __align__(16) u32 hbuf[2][64];        // i8 h, full 256 units, dbuf
    __shared__ float g_sh[512];
    __shared__ float m0sh;
    const int tid = threadIdx.x;
    const int p = blockIdx.x & 127, hf = blockIdx.x >> 7;
    const int b = p >> 1, dir = p & 1;
    const int r = tid >> 1, ch = tid & 1;
    const int g = r >> 7, ul = r & 127;
    const int R = g * 256 + hf * 128 + ul;           // gate row within this dir

    // --- weights: row R, cols [ch*128, ch*128+128) = u32 [ch*32, ch*32+32) ---
    const uint4* wrow4 = (const uint4*)(wq + (size_t)dir * 1024 * 64 + (size_t)R * 64 + ch * 32);
    uint4 w0 = wrow4[0], w1 = wrow4[1], w2 = wrow4[2], w3 = wrow4[3], w4 = wrow4[4], w5 = wrow4[5];
    wl[0][tid] = wrow4[6];
    wl[1][tid] = wrow4[7];
    const float dqrow = dqw[dir * 1024 + R];

    // --- state: gate wave (tid<64) owns units u0=hf*128+2*tid, u1=u0+1 ---
    float ca = 0.f, cb = 0.f;
    if (tid < 64) {
        const float* c0p = c0 + (size_t)dir * B_ * HD_ + (size_t)b * HD_ + hf * 128 + 2 * tid;
        ca = c0p[0]; cb = c0p[1];
        // h(0): full 256-unit quantize with dynamic scale (|h0| can exceed 1)
        float4 hv = ((const float4*)(h0 + (size_t)dir * B_ * HD_ + (size_t)b * HD_))[tid];
        float am = fmaxf(fmaxf(fabsf(hv.x), fabsf(hv.y)), fmaxf(fabsf(hv.z), fabsf(hv.w)));
#pragma unroll
        for (int off = 32; off >= 1; off >>= 1) am = fmaxf(am, __shfl_xor(am, off, 64));
        am = fmaxf(am, 1e-6f);
        float sc = 127.f / am;
        int q0 = ((int)rintf(hv.x * sc)) & 255, q1 = ((int)rintf(hv.y * sc)) & 255;
        int q2 = ((int)rintf(hv.z * sc)) & 255, q3 = ((int)rintf(hv.w * sc)) & 255;
        hbuf[0][tid] = (u32)(q0 | (q1 << 8) | (q2 << 16) | (q3 << 24));
        if (tid == 0) m0sh = am;
    }
    __syncthreads();
    const float m0v = m0sh;

    // --- z: even lanes own row r's preact (bias already folded by GEMM) ---
    const _Float16* Zr = Z + (size_t)b * T_ * 2048 + dir * 1024 + R;
    float zq = 0.f;
    if (ch == 0) zq = (float)Zr[(size_t)(dir ? T_ - 1 : 0) * 2048];

    u32* xh_my = xh + ((size_t)(p * 2 + hf)) * 64;           // 2 parity * 32
    const u32* xh_pt = xh + ((size_t)(p * 2 + (1 - hf))) * 64;
    u32* myflag = flags + p * 2 + hf;
    u32* pflag  = flags + p * 2 + (1 - hf);

    for (int s = 0; s < T_; ++s) {
        const int t = dir ? (T_ - 1 - s) : s;
        float zn = 0.f;
        if (ch == 0 && s + 1 < T_) zn = (float)Zr[(size_t)(dir ? t - 1 : t + 1) * 2048];
        // --- dots: 32 sdot4 against h(s) ---
        const uint4* hb = (const uint4*)&hbuf[s & 1][ch * 32];
        int a0 = 0, a1 = 0, a2 = 0, a3 = 0;
        {
            uint4 hA = hb[0], hB = hb[1], hC = hb[2], hD = hb[3];
            a0 = dotq(w0, hA, a0); a1 = dotq(w1, hB, a1);
            a2 = dotq(w2, hC, a2); a3 = dotq(w3, hD, a3);
        }
        {
            uint4 hE = hb[4], hF = hb[5], hG = hb[6], hH = hb[7];
            uint4 t0 = wl[0][tid], t1 = wl[1][tid];
            a0 = dotq(w4, hE, a0); a1 = dotq(w5, hF, a1);
            a2 = dotq(t0, hG, a2); a3 = dotq(t1, hH, a3);
        }
        int ai = (a0 + a1) + (a2 + a3);
        ai += __shfl_xor(ai, 1, 64);            // combine col-halves
        if (ch == 0) {
            float dq = dqrow * (s == 0 ? m0v : 1.f);
            g_sh[r] = (float)ai * dq + zq;
        }
        zq = zn;
        __syncthreads();                        // partials ready
        if (tid < 64) {
            // gates for 2 units; g_sh already dequanted + z-folded
            float2 gi = *(const float2*)&g_sh[0 * 128 + 2 * tid];
            float2 gf = *(const float2*)&g_sh[1 * 128 + 2 * tid];
            float2 gg = *(const float2*)&g_sh[2 * 128 + 2 * tid];
            float2 go = *(const float2*)&g_sh[3 * 128 + 2 * tid];
            ca = sigm(gf.x) * ca + sigm(gi.x) * tanh_f(gg.x);
            cb = sigm(gf.y) * cb + sigm(gi.y) * tanh_f(gg.y);
            float ha = sigm(go.x) * tanh_f(ca);
            float hb2 = sigm(go.y) * tanh_f(cb);
            u32 pk = (u32)(((int)rintf(ha * 127.f)) & 255) |
                     ((u32)(((int)rintf(hb2 * 127.f)) & 255) << 8);
            if (s + 1 < T_) {
                u32 ot = (u32)__shfl_xor((int)pk, 1, 64);
                if (!(tid & 1)) {               // even lanes publish packed u32
                    __hip_atomic_store(&xh_my[((s + 1) & 1) * 32 + (tid >> 1)],
                                       pk | (ot << 16), __ATOMIC_RELAXED, __HIP_MEMORY_SCOPE_AGENT);
                }
                if (tid == 0)
                    __hip_atomic_store(myflag, (u32)(s + 1), __ATOMIC_RELEASE, __HIP_MEMORY_SCOPE_AGENT);
            }
            ((unsigned short*)&hbuf[(s + 1) & 1][0])[hf * 64 + tid] = (unsigned short)pk;
            half2v hp; hp.x = (_Float16)ha; hp.y = (_Float16)hb2;
            *(u32*)(Hout + (size_t)(b * T_ + t) * H_ + dir * HD_ + hf * 128 + 2 * tid) =
                __builtin_bit_cast(u32, hp);
        } else if (tid >= 960 && tid < 992 && s + 1 < T_) {
            const int lane = tid - 960;
            const u32 tgt = (u32)(s + 1);
            while (__hip_atomic_load(pflag, __ATOMIC_ACQUIRE, __HIP_MEMORY_SCOPE_AGENT) < tgt) {}
            u32 v = __hip_atomic_load(&xh_pt[((s + 1) & 1) * 32 + lane],
                                      __ATOMIC_RELAXED, __HIP_MEMORY_SCOPE_AGENT);
            hbuf[(s + 1) & 1][(1 - hf) * 32 + lane] = v;
        }
        __syncthreads();                        // h(s+1) complete in LDS
    }
}

// ---------------- tag scores: out[m,kk] = H[m,:] . w_out[kk,:] + b_out[kk] ----------------
__global__ __launch_bounds__(256) void tag_k(const _Float16* __restrict__ Hs,
                                             const float* __restrict__ wout,
                                             const float* __restrict__ bout,
                                             float* __restrict__ out) {
    const int tid = threadIdx.x;
    const int mi = tid >> 4, kk = tid & 15;
    const int m = blockIdx.x * 16 + mi;
    const uint4* hrow = (const uint4*)(Hs + (size_t)m * H_);
    const float4* wrow = (const float4*)(wout + (size_t)kk * H_);
    float acc = 0.f;
#pragma unroll 8
    for (int i = 0; i < 64; ++i) {
        uint4 hv = hrow[i];
        float4 w0 = wrow[2 * i], w1 = wrow[2 * i + 1];
        half2v p0 = __builtin_bit_cast(half2v, hv.x), p1 = __builtin_bit_cast(half2v, hv.y);
        half2v p2 = __builtin_bit_cast(half2v, hv.z), p3 = __builtin_bit_cast(half2v, hv.w);
        acc += (float)p0.x * w0.x + (float)p0.y * w0.y + (float)p1.x * w0.z + (float)p1.y * w0.w
             + (float)p2.x * w1.x + (float)p2.y * w1.y + (float)p3.x * w1.z + (float)p3.y * w1.w;
    }
    out[(size_t)m * K_ + kk] = acc + bout[kk];
}

// ---------------- CRF forward (faithful to reference's cross-batch sum) ----------------
__global__ __launch_bounds__(1024) void crf_k(const float* __restrict__ tag,
                                              const float* __restrict__ trans,
                                              float* __restrict__ out) {
    __shared__ float albuf[2][64][17];
    const int tid = threadIdx.x;
    const int kn = tid >> 6, b = tid & 63;   // wave = next-tag, lane = batch
    float trow[16];
#pragma unroll
    for (int kp = 0; kp < 16; ++kp) trow[kp] = trans[kn * 16 + kp];
    albuf[0][b][kn] = (kn == START_) ? 0.f : NEG_;
    __syncthreads();
    int cur = 0;
    for (int t = 0; t < T_; ++t) {
        const float feat = tag[(size_t)(b * T_ + t) * K_ + kn];
        float v[16];
        float m = -3.4e38f;
#pragma unroll
        for (int kp = 0; kp < 16; ++kp) {
            v[kp] = albuf[cur][b][kp] + trow[kp];
            m = fmaxf(m, v[kp]);
        }
        float sm = 0.f;
#pragma unroll
        for (int kp = 0; kp < 16; ++kp) sm += __expf(v[kp] - m);
#pragma unroll
        for (int off = 32; off >= 1; off >>= 1) sm += __shfl_xor(sm, off, 64);
        albuf[cur ^ 1][b][kn] = feat + m + __logf(sm);
        __syncthreads();
        cur ^= 1;
    }
    const float term = albuf[cur][b][kn] + trans[STOP_ * 16 + kn];
    albuf[cur ^ 1][b][kn] = term;
    __syncthreads();
    if (tid < 64) {   // all in wave 0
        float mb = -3.4e38f;
#pragma unroll
        for (int k2 = 0; k2 < 16; ++k2) mb = fmaxf(mb, albuf[cur ^ 1][tid][k2]);
        float p = 0.f;
#pragma unroll
        for (int k2 = 0; k2 < 16; ++k2) p += __expf(albuf[cur ^ 1][tid][k2] - mb);
#pragma unroll
        for (int off = 32; off >= 1; off >>= 1) p += __shfl_xor(p, off, 64);
        out[(size_t)B_ * T_ * K_ + tid] = mb + __logf(p);
    }
}

extern "C" void kernel_launch(void* const* d_in, const int* in_sizes, int n_in,
                              void* d_out, int out_size, void* d_ws, size_t ws_size,
                              hipStream_t stream) {
    const int*   x     = (const int*)d_in[0];
    const float* emb   = (const float*)d_in[2];
    const float* w_ih  = (const float*)d_in[3];
    const float* w_hh  = (const float*)d_in[4];
    const float* b_ih  = (const float*)d_in[5];
    const float* b_hh  = (const float*)d_in[6];
    const float* h0    = (const float*)d_in[7];
    const float* c0    = (const float*)d_in[8];
    const float* w_out = (const float*)d_in[9];
    const float* b_out = (const float*)d_in[10];
    const float* trans = (const float*)d_in[11];
    float* out = (float*)d_out;

    // workspace layout (≈199 MB)
    char* ws = (char*)d_ws;
    u32*      wq    = (u32*)ws;                                   // 1 MB   [L][2][1024][64] i8-packed
    float*    dqw   = (float*)(ws + ((size_t)1 << 20));           // 16 KB  [L][2][1024]
    _Float16* wih16 = (_Float16*)(ws + ((size_t)2 << 20));        // 4 MB   [L][2048][512]
    float*    bsum  = (float*)(ws + ((size_t)6 << 20));           // 16 KB  [L][2048]
    u32*      xh    = (u32*)(ws + ((size_t)6 << 20) + (128 << 10)); // 64 KB [128][2][2][32]
    u32*      flags = (u32*)(ws + ((size_t)6 << 20) + (256 << 10)); // 2 KB  [L][128][2]
    _Float16* xe    = (_Float16*)(ws + ((size_t)7 << 20));        // 32 MB  [32768][512] (reused as H1)
    _Float16* Zb    = (_Float16*)(ws + ((size_t)39 << 20));       // 128 MB [32768][2048]
    _Float16* H0b   = (_Float16*)(ws + ((size_t)167 << 20));      // 32 MB  [32768][512]
    if (ws_size < ((size_t)199 << 20)) return;

    init_flags_k<<<1, 512, 0, stream>>>(flags);
    quant_whh_k<<<4096, 64, 0, stream>>>(w_hh, wq, dqw);
    cvt_f16_k<<<2048, 256, 0, stream>>>(w_ih, wih16, 2097152 / 4);
    bias_sum_k<<<16, 256, 0, stream>>>(b_ih, b_hh, bsum);
    embed_k<<<B_ * T_, 128, 0, stream>>>(x, emb, xe);

    // layer 0
    gemm_bt<<<(32768 / 128) * (2048 / 128), 256, 0, stream>>>(xe, wih16, bsum, Zb, 32768, 2048, 512);
    lstm_pair_k<<<256, 1024, 0, stream>>>(wq, dqw, h0, c0, Zb, H0b, xh, flags);
    // layer 1
    gemm_bt<<<(32768 / 128) * (2048 / 128), 256, 0, stream>>>(H0b, wih16 + (size_t)2048 * 512, bsum + 2048, Zb, 32768, 2048, 512);
    lstm_pair_k<<<256, 1024, 0, stream>>>(wq + (size_t)2048 * 64, dqw + 2048,
                                          h0 + 2 * B_ * HD_, c0 + 2 * B_ * HD_, Zb, xe /*H1*/,
                                          xh, flags + 256);
    // emissions + CRF
    tag_k<<<32768 / 16, 256, 0, stream>>>(xe, w_out, b_out, out);
    crf_k<<<1, 1024, 0, stream>>>(out, trans, out);
}

// Round 6
// 1967.358 us; speedup vs baseline: 5.3218x; 5.3218x over previous
//
#include <hip/hip_runtime.h>

#define B_ 64
#define T_ 512
#define E_ 512
#define HD_ 256
#define H_ 512
#define K_ 16
#define NEG_ (-10000.0f)
#define START_ 13
#define STOP_ 14

typedef unsigned int u32;
using half8  = __attribute__((ext_vector_type(8))) _Float16;
using f32x4  = __attribute__((ext_vector_type(4))) float;
using half2v = __attribute__((ext_vector_type(2))) _Float16;

__device__ __forceinline__ int dot4i8(u32 a, u32 b, int c) {
#if __has_builtin(__builtin_amdgcn_sdot4)
    return __builtin_amdgcn_sdot4((int)a, (int)b, c, false);
#else
    int r = c;
#pragma unroll
    for (int i = 0; i < 4; ++i) {
        int xa = ((int)a << (24 - 8 * i)) >> 24;
        int xb = ((int)b << (24 - 8 * i)) >> 24;
        r += xa * xb;
    }
    return r;
#endif
}
__device__ __forceinline__ int dotq(uint4 w, uint4 h, int a) {
    a = dot4i8(w.x, h.x, a); a = dot4i8(w.y, h.y, a);
    a = dot4i8(w.z, h.z, a); a = dot4i8(w.w, h.w, a);
    return a;
}
__device__ __forceinline__ float sigm(float x) { return 1.f / (1.f + __expf(-x)); }
__device__ __forceinline__ float tanh_f(float x) {
    float a = fabsf(x);
    float e = __expf(-2.f * a);
    float t = (1.f - e) / (1.f + e);
    return x < 0.f ? -t : t;
}

// ---------------- converters ----------------
__global__ void cvt_f16_k(const float* __restrict__ src, _Float16* __restrict__ dst, int n4) {
    int i = blockIdx.x * blockDim.x + threadIdx.x;
    if (i < n4) {
        float4 v = ((const float4*)src)[i];
        half2v a; a.x = (_Float16)v.x; a.y = (_Float16)v.y;
        half2v b; b.x = (_Float16)v.z; b.y = (_Float16)v.w;
        ((u32*)dst)[2 * i]     = __builtin_bit_cast(u32, a);
        ((u32*)dst)[2 * i + 1] = __builtin_bit_cast(u32, b);
    }
}
__global__ void bias_sum_k(const float* __restrict__ bih, const float* __restrict__ bhh,
                           float* __restrict__ bs) {
    int i = blockIdx.x * blockDim.x + threadIdx.x;
    if (i < 4096) bs[i] = bih[i] + bhh[i];
}

// ---------------- W_hh row-scaled int8 quantization: one 64-thread block per row ------
__global__ void quant_whh_k(const float* __restrict__ whh,   // [4096][256]
                            u32* __restrict__ wq,            // [4096][64] packed i8
                            float* __restrict__ dqw) {       // [4096] dequant = rowmax/127^2
    const int row = blockIdx.x, lane = threadIdx.x;          // 64 lanes
    const float4 v = ((const float4*)(whh + (size_t)row * 256))[lane];
    float m = fmaxf(fmaxf(fabsf(v.x), fabsf(v.y)), fmaxf(fabsf(v.z), fabsf(v.w)));
#pragma unroll
    for (int off = 32; off >= 1; off >>= 1) m = fmaxf(m, __shfl_xor(m, off, 64));
    m = fmaxf(m, 1e-8f);
    const float s = 127.f / m;
    int b0 = ((int)rintf(v.x * s)) & 255;
    int b1 = ((int)rintf(v.y * s)) & 255;
    int b2 = ((int)rintf(v.z * s)) & 255;
    int b3 = ((int)rintf(v.w * s)) & 255;
    wq[(size_t)row * 64 + lane] = (u32)(b0 | (b1 << 8) | (b2 << 16) | (b3 << 24));
    if (lane == 0) dqw[row] = m / (127.f * 127.f);
}

// ---------------- embedding gather + cast to f16 ----------------
__global__ void embed_k(const int* __restrict__ x, const float* __restrict__ emb,
                        _Float16* __restrict__ xe) {
    int m = blockIdx.x;                  // 0..32767 = b*T + t
    int row = x[m];
    int c = threadIdx.x * 4;             // 128 threads * 4 = 512
    float4 v = *(const float4*)(emb + (size_t)row * E_ + c);
    half2v p0; p0.x = (_Float16)v.x; p0.y = (_Float16)v.y;
    half2v p1; p1.x = (_Float16)v.z; p1.y = (_Float16)v.w;
    u32* dst = (u32*)(xe + (size_t)m * E_) + threadIdx.x * 2;
    dst[0] = __builtin_bit_cast(u32, p0);
    dst[1] = __builtin_bit_cast(u32, p1);
}

// ---------------- f16 MFMA GEMM:  C[m,n] = sum_k A[m,k]*Bw[n,k] + bias[n]  (C f16) -----
__global__ __launch_bounds__(256) void gemm_bt(const _Float16* __restrict__ A,
                                               const _Float16* __restrict__ Bw,
                                               const float* __restrict__ bsum,
                                               _Float16* __restrict__ C,
                                               int M, int N, int Kd) {
    __shared__ __align__(16) _Float16 As[128 * 64];
    __shared__ __align__(16) _Float16 Bs[128 * 64];
    const int nTn = N >> 7;
    const int tm = blockIdx.x / nTn, tn = blockIdx.x % nTn;
    const int tid = threadIdx.x;
    const int lane = tid & 63, wave = tid >> 6;
    const int wr = wave >> 1, wc = wave & 1;      // 2x2 waves of 64x64
    f32x4 acc[4][4];
#pragma unroll
    for (int i = 0; i < 4; ++i)
#pragma unroll
        for (int j = 0; j < 4; ++j) acc[i][j] = f32x4{0.f, 0.f, 0.f, 0.f};
    const int lr = lane & 15, lk = (lane >> 4) * 8;

    for (int k0 = 0; k0 < Kd; k0 += 64) {
#pragma unroll
        for (int r = 0; r < 4; ++r) {
            int c = r * 256 + tid;                     // chunk id, 16B each
            const _Float16* srcA = A + (size_t)(tm * 128 + (c >> 3)) * Kd + k0 + (c & 7) * 8;
            const _Float16* srcB = Bw + (size_t)(tn * 128 + (c >> 3)) * Kd + k0 + (c & 7) * 8;
            _Float16* dA = &As[(size_t)(r * 256 + wave * 64) * 8];
            _Float16* dB = &Bs[(size_t)(r * 256 + wave * 64) * 8];
            __builtin_amdgcn_global_load_lds((const __attribute__((address_space(1))) void*)srcA,
                                             (__attribute__((address_space(3))) void*)dA, 16, 0, 0);
            __builtin_amdgcn_global_load_lds((const __attribute__((address_space(1))) void*)srcB,
                                             (__attribute__((address_space(3))) void*)dB, 16, 0, 0);
        }
        __syncthreads();
#pragma unroll
        for (int kk = 0; kk < 2; ++kk) {
            half8 av[4], bv[4];
#pragma unroll
            for (int i = 0; i < 4; ++i)
                av[i] = *(const half8*)&As[(wr * 64 + i * 16 + lr) * 64 + kk * 32 + lk];
#pragma unroll
            for (int j = 0; j < 4; ++j)
                bv[j] = *(const half8*)&Bs[(wc * 64 + j * 16 + lr) * 64 + kk * 32 + lk];
#pragma unroll
            for (int i = 0; i < 4; ++i)
#pragma unroll
                for (int j = 0; j < 4; ++j)
                    acc[i][j] = __builtin_amdgcn_mfma_f32_16x16x32_f16(av[i], bv[j], acc[i][j], 0, 0, 0);
        }
        __syncthreads();
    }
    const int mq = (lane >> 4) * 4;
#pragma unroll
    for (int i = 0; i < 4; ++i)
#pragma unroll
        for (int j = 0; j < 4; ++j) {
            int m0 = tm * 128 + wr * 64 + i * 16 + mq;
            int n0 = tn * 128 + wc * 64 + j * 16 + lr;
            float bv = bsum[n0];
#pragma unroll
            for (int q = 0; q < 4; ++q)
                C[(size_t)(m0 + q) * N + n0] = (_Float16)(acc[i][j][q] + bv);
        }
}

// ---------------- LSTM recurrence, 512 threads, all-register int8 weights -------------
// Block = (b, dir), 128 blocks of 512 threads (8 waves -> 2 waves/SIMD, so the HW VGPR
// ceiling is 256; demand ~150). Thread u owns FULL 256-col rows u and u+512:
//   u in [0,256):   rows u (gate i, unit u)      and u+512 (gate g, unit u)
//   u in [256,512): rows u (gate f, unit u-256)  and u+512 (gate o, unit u-256)
// Full-row dots => no cross-lane reduce, no LDS weight reads (128 weight-u32 in VGPRs).
// h (256 x i8 = 64 u32) is read as 16 broadcast b128 loads; double-buffered by parity.
// R5 lesson: cross-CU per-step handshakes cost ~10us/step — stay within one CU.
__global__ __attribute__((amdgpu_flat_work_group_size(512, 512), amdgpu_waves_per_eu(2, 2)))
void lstm_layer_k(
    const u32* __restrict__ wq,           // [2][1024][64] packed i8 (this layer)
    const float* __restrict__ dqw,        // [2][1024] rowmax/127^2 (this layer)
    const float* __restrict__ h0,         // [2][64][256]
    const float* __restrict__ c0,         // [2][64][256]
    const _Float16* __restrict__ Z,       // [32768][2048] f16 preacts (x@Wih + bias)
    _Float16* __restrict__ Hout) {        // [32768][512] f16
    __shared__ __align__(16) u32 hbuf[2][64];   // i8 h, 256 units, parity double-buffer
    __shared__ float g_sh[1024];
    __shared__ float m0sh;
    const int tid = threadIdx.x;                 // 0..511
    const int b = blockIdx.x >> 1, dir = blockIdx.x & 1;
    const int R0 = tid, R1 = tid + 512;

    // --- weights: two full rows, register-resident (16+16 uint4) ---
    const uint4* w4 = (const uint4*)(wq + (size_t)dir * 1024 * 64);
    uint4 wa[16], wb[16];
#pragma unroll
    for (int i = 0; i < 16; ++i) wa[i] = w4[(size_t)R0 * 16 + i];
#pragma unroll
    for (int i = 0; i < 16; ++i) wb[i] = w4[(size_t)R1 * 16 + i];
    const float dq0 = dqw[dir * 1024 + R0];
    const float dq1 = dqw[dir * 1024 + R1];

    // --- state: threads 0..255 own c[unit]; wave 0 quantizes h0 with dynamic scale ---
    float c = 0.f;
    if (tid < 256) c = c0[(size_t)dir * B_ * HD_ + b * HD_ + tid];
    if (tid < 64) {
        float4 hv = ((const float4*)(h0 + (size_t)dir * B_ * HD_ + (size_t)b * HD_))[tid];
        float am = fmaxf(fmaxf(fabsf(hv.x), fabsf(hv.y)), fmaxf(fabsf(hv.z), fabsf(hv.w)));
#pragma unroll
        for (int off = 32; off >= 1; off >>= 1) am = fmaxf(am, __shfl_xor(am, off, 64));
        am = fmaxf(am, 1e-6f);
        float sc = 127.f / am;
        int q0 = ((int)rintf(hv.x * sc)) & 255, q1 = ((int)rintf(hv.y * sc)) & 255;
        int q2 = ((int)rintf(hv.z * sc)) & 255, q3 = ((int)rintf(hv.w * sc)) & 255;
        hbuf[0][tid] = (u32)(q0 | (q1 << 8) | (q2 << 16) | (q3 << 24));
        if (tid == 0) m0sh = am;
    }
    // --- z: this thread's two rows, prefetched one step ahead (coalesced) ---
    const _Float16* Zr = Z + (size_t)b * T_ * 2048 + dir * 1024;
    const int t0 = dir ? (T_ - 1) : 0;
    float z0 = (float)Zr[(size_t)t0 * 2048 + R0];
    float z1 = (float)Zr[(size_t)t0 * 2048 + R1];
    __syncthreads();
    const float m0v = m0sh;

    for (int s = 0; s < T_; ++s) {
        const int t = dir ? (T_ - 1 - s) : s;
        float zn0 = 0.f, zn1 = 0.f;
        if (s + 1 < T_) {
            const int tn = dir ? (t - 1) : (t + 1);
            zn0 = (float)Zr[(size_t)tn * 2048 + R0];
            zn1 = (float)Zr[(size_t)tn * 2048 + R1];
        }
        // --- two full-row dots: 32 sdot4 each, h via broadcast b128 reads ---
        const uint4* hb = (const uint4*)&hbuf[s & 1][0];
        int a0 = 0, a1 = 0;
#pragma unroll
        for (int i = 0; i < 16; ++i) {
            uint4 hv = hb[i];
            a0 = dotq(wa[i], hv, a0);
            a1 = dotq(wb[i], hv, a1);
        }
        const float sc = (s == 0) ? m0v : 1.f;
        g_sh[R0] = (float)a0 * (dq0 * sc) + z0;
        g_sh[R1] = (float)a1 * (dq1 * sc) + z1;
        z0 = zn0; z1 = zn1;
        __syncthreads();                        // preacts ready
        if (tid < 256) {
            float gi = g_sh[tid], gf = g_sh[tid + 256];
            float gg = g_sh[tid + 512], go = g_sh[tid + 768];
            c = sigm(gf) * c + sigm(gi) * tanh_f(gg);
            float h = sigm(go) * tanh_f(c);
            Hout[(size_t)(b * T_ + t) * H_ + dir * HD_ + tid] = (_Float16)h;
            ((signed char*)&hbuf[(s + 1) & 1][0])[tid] = (signed char)(int)rintf(h * 127.f);
        }
        __syncthreads();                        // h(s+1) complete
    }
}

// ---------------- tag scores: out[m,kk] = H[m,:] . w_out[kk,:] + b_out[kk] ----------------
__global__ __launch_bounds__(256) void tag_k(const _Float16* __restrict__ Hs,
                                             const float* __restrict__ wout,
                                             const float* __restrict__ bout,
                                             float* __restrict__ out) {
    const int tid = threadIdx.x;
    const int mi = tid >> 4, kk = tid & 15;
    const int m = blockIdx.x * 16 + mi;
    const uint4* hrow = (const uint4*)(Hs + (size_t)m * H_);
    const float4* wrow = (const float4*)(wout + (size_t)kk * H_);
    float acc = 0.f;
#pragma unroll 8
    for (int i = 0; i < 64; ++i) {
        uint4 hv = hrow[i];
        float4 w0 = wrow[2 * i], w1 = wrow[2 * i + 1];
        half2v p0 = __builtin_bit_cast(half2v, hv.x), p1 = __builtin_bit_cast(half2v, hv.y);
        half2v p2 = __builtin_bit_cast(half2v, hv.z), p3 = __builtin_bit_cast(half2v, hv.w);
        acc += (float)p0.x * w0.x + (float)p0.y * w0.y + (float)p1.x * w0.z + (float)p1.y * w0.w
             + (float)p2.x * w1.x + (float)p2.y * w1.y + (float)p3.x * w1.z + (float)p3.y * w1.w;
    }
    out[(size_t)m * K_ + kk] = acc + bout[kk];
}

// ---------------- CRF forward (faithful to reference's cross-batch sum) ----------------
__global__ __launch_bounds__(1024) void crf_k(const float* __restrict__ tag,
                                              const float* __restrict__ trans,
                                              float* __restrict__ out) {
    __shared__ float albuf[2][64][17];
    const int tid = threadIdx.x;
    const int kn = tid >> 6, b = tid & 63;   // wave = next-tag, lane = batch
    float trow[16];
#pragma unroll
    for (int kp = 0; kp < 16; ++kp) trow[kp] = trans[kn * 16 + kp];
    albuf[0][b][kn] = (kn == START_) ? 0.f : NEG_;
    __syncthreads();
    int cur = 0;
    for (int t = 0; t < T_; ++t) {
        const float feat = tag[(size_t)(b * T_ + t) * K_ + kn];
        float v[16];
        float m = -3.4e38f;
#pragma unroll
        for (int kp = 0; kp < 16; ++kp) {
            v[kp] = albuf[cur][b][kp] + trow[kp];
            m = fmaxf(m, v[kp]);
        }
        float sm = 0.f;
#pragma unroll
        for (int kp = 0; kp < 16; ++kp) sm += __expf(v[kp] - m);
#pragma unroll
        for (int off = 32; off >= 1; off >>= 1) sm += __shfl_xor(sm, off, 64);
        albuf[cur ^ 1][b][kn] = feat + m + __logf(sm);
        __syncthreads();
        cur ^= 1;
    }
    const float term = albuf[cur][b][kn] + trans[STOP_ * 16 + kn];
    albuf[cur ^ 1][b][kn] = term;
    __syncthreads();
    if (tid < 64) {   // all in wave 0
        float mb = -3.4e38f;
#pragma unroll
        for (int k2 = 0; k2 < 16; ++k2) mb = fmaxf(mb, albuf[cur ^ 1][tid][k2]);
        float p = 0.f;
#pragma unroll
        for (int k2 = 0; k2 < 16; ++k2) p += __expf(albuf[cur ^ 1][tid][k2] - mb);
#pragma unroll
        for (int off = 32; off >= 1; off >>= 1) p += __shfl_xor(p, off, 64);
        out[(size_t)B_ * T_ * K_ + tid] = mb + __logf(p);
    }
}

extern "C" void kernel_launch(void* const* d_in, const int* in_sizes, int n_in,
                              void* d_out, int out_size, void* d_ws, size_t ws_size,
                              hipStream_t stream) {
    const int*   x     = (const int*)d_in[0];
    const float* emb   = (const float*)d_in[2];
    const float* w_ih  = (const float*)d_in[3];
    const float* w_hh  = (const float*)d_in[4];
    const float* b_ih  = (const float*)d_in[5];
    const float* b_hh  = (const float*)d_in[6];
    const float* h0    = (const float*)d_in[7];
    const float* c0    = (const float*)d_in[8];
    const float* w_out = (const float*)d_in[9];
    const float* b_out = (const float*)d_in[10];
    const float* trans = (const float*)d_in[11];
    float* out = (float*)d_out;

    // workspace layout (≈199 MB)
    char* ws = (char*)d_ws;
    u32*      wq    = (u32*)ws;                                   // 1 MB   [L][2][1024][64] i8-packed
    float*    dqw   = (float*)(ws + ((size_t)1 << 20));           // 16 KB  [L][2][1024]
    _Float16* wih16 = (_Float16*)(ws + ((size_t)2 << 20));        // 4 MB   [L][2048][512]
    float*    bsum  = (float*)(ws + ((size_t)6 << 20));           // 16 KB  [L][2048]
    _Float16* xe    = (_Float16*)(ws + ((size_t)7 << 20));        // 32 MB  [32768][512] (reused as H1)
    _Float16* Zb    = (_Float16*)(ws + ((size_t)39 << 20));       // 128 MB [32768][2048]
    _Float16* H0b   = (_Float16*)(ws + ((size_t)167 << 20));      // 32 MB  [32768][512]
    if (ws_size < ((size_t)199 << 20)) return;

    quant_whh_k<<<4096, 64, 0, stream>>>(w_hh, wq, dqw);
    cvt_f16_k<<<2048, 256, 0, stream>>>(w_ih, wih16, 2097152 / 4);
    bias_sum_k<<<16, 256, 0, stream>>>(b_ih, b_hh, bsum);
    embed_k<<<B_ * T_, 128, 0, stream>>>(x, emb, xe);

    // layer 0
    gemm_bt<<<(32768 / 128) * (2048 / 128), 256, 0, stream>>>(xe, wih16, bsum, Zb, 32768, 2048, 512);
    lstm_layer_k<<<128, 512, 0, stream>>>(wq, dqw, h0, c0, Zb, H0b);
    // layer 1
    gemm_bt<<<(32768 / 128) * (2048 / 128), 256, 0, stream>>>(H0b, wih16 + (size_t)2048 * 512, bsum + 2048, Zb, 32768, 2048, 512);
    lstm_layer_k<<<128, 512, 0, stream>>>(wq + (size_t)2048 * 64, dqw + 2048,
                                          h0 + 2 * B_ * HD_, c0 + 2 * B_ * HD_, Zb, xe /*H1*/);
    // emissions + CRF
    tag_k<<<32768 / 16, 256, 0, stream>>>(xe, w_out, b_out, out);
    crf_k<<<1, 1024, 0, stream>>>(out, trans, out);
}

// Round 7
// 1946.322 us; speedup vs baseline: 5.3793x; 1.0108x over previous
//
#include <hip/hip_runtime.h>

#define B_ 64
#define T_ 512
#define E_ 512
#define HD_ 256
#define H_ 512
#define K_ 16
#define NEG_ (-10000.0f)
#define START_ 13
#define STOP_ 14

typedef unsigned int u32;
using half8  = __attribute__((ext_vector_type(8))) _Float16;
using f32x4  = __attribute__((ext_vector_type(4))) float;
using half2v = __attribute__((ext_vector_type(2))) _Float16;

__device__ __forceinline__ int dot4i8(u32 a, u32 b, int c) {
#if __has_builtin(__builtin_amdgcn_sdot4)
    return __builtin_amdgcn_sdot4((int)a, (int)b, c, false);
#else
    int r = c;
#pragma unroll
    for (int i = 0; i < 4; ++i) {
        int xa = ((int)a << (24 - 8 * i)) >> 24;
        int xb = ((int)b << (24 - 8 * i)) >> 24;
        r += xa * xb;
    }
    return r;
#endif
}
__device__ __forceinline__ int dotq(uint4 w, uint4 h, int a) {
    a = dot4i8(w.x, h.x, a); a = dot4i8(w.y, h.y, a);
    a = dot4i8(w.z, h.z, a); a = dot4i8(w.w, h.w, a);
    return a;
}
__device__ __forceinline__ float sigm(float x) { return 1.f / (1.f + __expf(-x)); }
__device__ __forceinline__ float tanh_f(float x) {
    float a = fabsf(x);
    float e = __expf(-2.f * a);
    float t = (1.f - e) / (1.f + e);
    return x < 0.f ? -t : t;
}

// ---------------- converters ----------------
__global__ void cvt_f16_k(const float* __restrict__ src, _Float16* __restrict__ dst, int n4) {
    int i = blockIdx.x * blockDim.x + threadIdx.x;
    if (i < n4) {
        float4 v = ((const float4*)src)[i];
        half2v a; a.x = (_Float16)v.x; a.y = (_Float16)v.y;
        half2v b; b.x = (_Float16)v.z; b.y = (_Float16)v.w;
        ((u32*)dst)[2 * i]     = __builtin_bit_cast(u32, a);
        ((u32*)dst)[2 * i + 1] = __builtin_bit_cast(u32, b);
    }
}
__global__ void bias_sum_k(const float* __restrict__ bih, const float* __restrict__ bhh,
                           float* __restrict__ bs) {
    int i = blockIdx.x * blockDim.x + threadIdx.x;
    if (i < 4096) bs[i] = bih[i] + bhh[i];
}

// ---------------- W_hh row-scaled int8 quantization: one 64-thread block per row ------
__global__ void quant_whh_k(const float* __restrict__ whh,   // [4096][256]
                            u32* __restrict__ wq,            // [4096][64] packed i8
                            float* __restrict__ dqw) {       // [4096] dequant = rowmax/127^2
    const int row = blockIdx.x, lane = threadIdx.x;          // 64 lanes
    const float4 v = ((const float4*)(whh + (size_t)row * 256))[lane];
    float m = fmaxf(fmaxf(fabsf(v.x), fabsf(v.y)), fmaxf(fabsf(v.z), fabsf(v.w)));
#pragma unroll
    for (int off = 32; off >= 1; off >>= 1) m = fmaxf(m, __shfl_xor(m, off, 64));
    m = fmaxf(m, 1e-8f);
    const float s = 127.f / m;
    int b0 = ((int)rintf(v.x * s)) & 255;
    int b1 = ((int)rintf(v.y * s)) & 255;
    int b2 = ((int)rintf(v.z * s)) & 255;
    int b3 = ((int)rintf(v.w * s)) & 255;
    wq[(size_t)row * 64 + lane] = (u32)(b0 | (b1 << 8) | (b2 << 16) | (b3 << 24));
    if (lane == 0) dqw[row] = m / (127.f * 127.f);
}

// ---------------- embedding gather + cast to f16 ----------------
__global__ void embed_k(const int* __restrict__ x, const float* __restrict__ emb,
                        _Float16* __restrict__ xe) {
    int m = blockIdx.x;                  // 0..32767 = b*T + t
    int row = x[m];
    int c = threadIdx.x * 4;             // 128 threads * 4 = 512
    float4 v = *(const float4*)(emb + (size_t)row * E_ + c);
    half2v p0; p0.x = (_Float16)v.x; p0.y = (_Float16)v.y;
    half2v p1; p1.x = (_Float16)v.z; p1.y = (_Float16)v.w;
    u32* dst = (u32*)(xe + (size_t)m * E_) + threadIdx.x * 2;
    dst[0] = __builtin_bit_cast(u32, p0);
    dst[1] = __builtin_bit_cast(u32, p1);
}

// ---------------- f16 MFMA GEMM:  C[m,n] = sum_k A[m,k]*Bw[n,k] + bias[n]  (C f16) -----
__global__ __launch_bounds__(256) void gemm_bt(const _Float16* __restrict__ A,
                                               const _Float16* __restrict__ Bw,
                                               const float* __restrict__ bsum,
                                               _Float16* __restrict__ C,
                                               int M, int N, int Kd) {
    __shared__ __align__(16) _Float16 As[128 * 64];
    __shared__ __align__(16) _Float16 Bs[128 * 64];
    const int nTn = N >> 7;
    const int tm = blockIdx.x / nTn, tn = blockIdx.x % nTn;
    const int tid = threadIdx.x;
    const int lane = tid & 63, wave = tid >> 6;
    const int wr = wave >> 1, wc = wave & 1;      // 2x2 waves of 64x64
    f32x4 acc[4][4];
#pragma unroll
    for (int i = 0; i < 4; ++i)
#pragma unroll
        for (int j = 0; j < 4; ++j) acc[i][j] = f32x4{0.f, 0.f, 0.f, 0.f};
    const int lr = lane & 15, lk = (lane >> 4) * 8;

    for (int k0 = 0; k0 < Kd; k0 += 64) {
#pragma unroll
        for (int r = 0; r < 4; ++r) {
            int c = r * 256 + tid;                     // chunk id, 16B each
            const _Float16* srcA = A + (size_t)(tm * 128 + (c >> 3)) * Kd + k0 + (c & 7) * 8;
            const _Float16* srcB = Bw + (size_t)(tn * 128 + (c >> 3)) * Kd + k0 + (c & 7) * 8;
            _Float16* dA = &As[(size_t)(r * 256 + wave * 64) * 8];
            _Float16* dB = &Bs[(size_t)(r * 256 + wave * 64) * 8];
            __builtin_amdgcn_global_load_lds((const __attribute__((address_space(1))) void*)srcA,
                                             (__attribute__((address_space(3))) void*)dA, 16, 0, 0);
            __builtin_amdgcn_global_load_lds((const __attribute__((address_space(1))) void*)srcB,
                                             (__attribute__((address_space(3))) void*)dB, 16, 0, 0);
        }
        __syncthreads();
#pragma unroll
        for (int kk = 0; kk < 2; ++kk) {
            half8 av[4], bv[4];
#pragma unroll
            for (int i = 0; i < 4; ++i)
                av[i] = *(const half8*)&As[(wr * 64 + i * 16 + lr) * 64 + kk * 32 + lk];
#pragma unroll
            for (int j = 0; j < 4; ++j)
                bv[j] = *(const half8*)&Bs[(wc * 64 + j * 16 + lr) * 64 + kk * 32 + lk];
#pragma unroll
            for (int i = 0; i < 4; ++i)
#pragma unroll
                for (int j = 0; j < 4; ++j)
                    acc[i][j] = __builtin_amdgcn_mfma_f32_16x16x32_f16(av[i], bv[j], acc[i][j], 0, 0, 0);
        }
        __syncthreads();
    }
    const int mq = (lane >> 4) * 4;
#pragma unroll
    for (int i = 0; i < 4; ++i)
#pragma unroll
        for (int j = 0; j < 4; ++j) {
            int m0 = tm * 128 + wr * 64 + i * 16 + mq;
            int n0 = tn * 128 + wc * 64 + j * 16 + lr;
            float bv = bsum[n0];
#pragma unroll
            for (int q = 0; q < 4; ++q)
                C[(size_t)(m0 + q) * N + n0] = (_Float16)(acc[i][j][q] + bv);
        }
}

// ---------------- LSTM recurrence, 512 threads, all-register int8 weights -------------
// Block = (b, dir), 128 blocks of 512 threads (8 waves -> 2 waves/SIMD; VGPR ceiling 256,
// demand ~160). Thread u owns FULL 256-col rows u and u+512. Full-row dots => no
// cross-lane reduce, no LDS weight traffic. h (256 x i8 = 64 u32) read as broadcast b128.
// R6 lesson: VGPR_Count=88 proved the compiler REMATERIALIZED ~half the weight loads
// inside the T-loop (wq is const __restrict__, so re-loading is legal). Fix: asm
// keep-live severs the SSA link load->use, forcing true residency (rule 17).
__global__ __attribute__((amdgpu_flat_work_group_size(512, 512), amdgpu_waves_per_eu(2, 2)))
void lstm_layer_k(
    const u32* __restrict__ wq,           // [2][1024][64] packed i8 (this layer)
    const float* __restrict__ dqw,        // [2][1024] rowmax/127^2 (this layer)
    const float* __restrict__ h0,         // [2][64][256]
    const float* __restrict__ c0,         // [2][64][256]
    const _Float16* __restrict__ Z,       // [32768][2048] f16 preacts (x@Wih + bias)
    _Float16* __restrict__ Hout) {        // [32768][512] f16
    __shared__ __align__(16) u32 hbuf[2][64];   // i8 h, 256 units, parity double-buffer
    __shared__ float g_sh[1024];
    __shared__ float m0sh;
    const int tid = threadIdx.x;                 // 0..511
    const int b = blockIdx.x >> 1, dir = blockIdx.x & 1;
    const int R0 = tid, R1 = tid + 512;

    // --- weights: two full rows, register-resident (16+16 uint4) ---
    const uint4* w4 = (const uint4*)(wq + (size_t)dir * 1024 * 64);
    uint4 wa[16], wb[16];
#pragma unroll
    for (int i = 0; i < 16; ++i) wa[i] = w4[(size_t)R0 * 16 + i];
#pragma unroll
    for (int i = 0; i < 16; ++i) wb[i] = w4[(size_t)R1 * 16 + i];
    // keep-live: compiler must hold these (not re-load from global each step)
#pragma unroll
    for (int i = 0; i < 16; ++i) {
        asm volatile("" : "+v"(wa[i].x), "+v"(wa[i].y), "+v"(wa[i].z), "+v"(wa[i].w));
        asm volatile("" : "+v"(wb[i].x), "+v"(wb[i].y), "+v"(wb[i].z), "+v"(wb[i].w));
    }
    const float dq0 = dqw[dir * 1024 + R0];
    const float dq1 = dqw[dir * 1024 + R1];

    // --- state: threads 0..255 own c[unit]; wave 0 quantizes h0 with dynamic scale ---
    float c = 0.f;
    if (tid < 256) c = c0[(size_t)dir * B_ * HD_ + b * HD_ + tid];
    if (tid < 64) {
        float4 hv = ((const float4*)(h0 + (size_t)dir * B_ * HD_ + (size_t)b * HD_))[tid];
        float am = fmaxf(fmaxf(fabsf(hv.x), fabsf(hv.y)), fmaxf(fabsf(hv.z), fabsf(hv.w)));
#pragma unroll
        for (int off = 32; off >= 1; off >>= 1) am = fmaxf(am, __shfl_xor(am, off, 64));
        am = fmaxf(am, 1e-6f);
        float sc = 127.f / am;
        int q0 = ((int)rintf(hv.x * sc)) & 255, q1 = ((int)rintf(hv.y * sc)) & 255;
        int q2 = ((int)rintf(hv.z * sc)) & 255, q3 = ((int)rintf(hv.w * sc)) & 255;
        hbuf[0][tid] = (u32)(q0 | (q1 << 8) | (q2 << 16) | (q3 << 24));
        if (tid == 0) m0sh = am;
    }
    // --- z: this thread's two rows, prefetched one step ahead (coalesced) ---
    const _Float16* Zr = Z + (size_t)b * T_ * 2048 + dir * 1024;
    const int t0 = dir ? (T_ - 1) : 0;
    float z0 = (float)Zr[(size_t)t0 * 2048 + R0];
    float z1 = (float)Zr[(size_t)t0 * 2048 + R1];
    __syncthreads();
    const float m0v = m0sh;

    for (int s = 0; s < T_; ++s) {
        const int t = dir ? (T_ - 1 - s) : s;
        float zn0 = 0.f, zn1 = 0.f;
        if (s + 1 < T_) {
            const int tn = dir ? (t - 1) : (t + 1);
            zn0 = (float)Zr[(size_t)tn * 2048 + R0];
            zn1 = (float)Zr[(size_t)tn * 2048 + R1];
        }
        // --- two full-row dots: 32 sdot4 each, h via broadcast b128 reads ---
        const uint4* hb = (const uint4*)&hbuf[s & 1][0];
        int a0 = 0, a1 = 0;
#pragma unroll
        for (int i = 0; i < 16; ++i) {
            uint4 hv = hb[i];
            a0 = dotq(wa[i], hv, a0);
            a1 = dotq(wb[i], hv, a1);
        }
        const float sc = (s == 0) ? m0v : 1.f;
        g_sh[R0] = (float)a0 * (dq0 * sc) + z0;
        g_sh[R1] = (float)a1 * (dq1 * sc) + z1;
        z0 = zn0; z1 = zn1;
        __syncthreads();                        // preacts ready
        if (tid < 256) {
            float gi = g_sh[tid], gf = g_sh[tid + 256];
            float gg = g_sh[tid + 512], go = g_sh[tid + 768];
            c = sigm(gf) * c + sigm(gi) * tanh_f(gg);
            float h = sigm(go) * tanh_f(c);
            Hout[(size_t)(b * T_ + t) * H_ + dir * HD_ + tid] = (_Float16)h;
            ((signed char*)&hbuf[(s + 1) & 1][0])[tid] = (signed char)(int)rintf(h * 127.f);
        }
        __syncthreads();                        // h(s+1) complete
    }
}

// ---------------- tag scores: out[m,kk] = H[m,:] . w_out[kk,:] + b_out[kk] ----------------
__global__ __launch_bounds__(256) void tag_k(const _Float16* __restrict__ Hs,
                                             const float* __restrict__ wout,
                                             const float* __restrict__ bout,
                                             float* __restrict__ out) {
    const int tid = threadIdx.x;
    const int mi = tid >> 4, kk = tid & 15;
    const int m = blockIdx.x * 16 + mi;
    const uint4* hrow = (const uint4*)(Hs + (size_t)m * H_);
    const float4* wrow = (const float4*)(wout + (size_t)kk * H_);
    float acc = 0.f;
#pragma unroll 8
    for (int i = 0; i < 64; ++i) {
        uint4 hv = hrow[i];
        float4 w0 = wrow[2 * i], w1 = wrow[2 * i + 1];
        half2v p0 = __builtin_bit_cast(half2v, hv.x), p1 = __builtin_bit_cast(half2v, hv.y);
        half2v p2 = __builtin_bit_cast(half2v, hv.z), p3 = __builtin_bit_cast(half2v, hv.w);
        acc += (float)p0.x * w0.x + (float)p0.y * w0.y + (float)p1.x * w0.z + (float)p1.y * w0.w
             + (float)p2.x * w1.x + (float)p2.y * w1.y + (float)p3.x * w1.z + (float)p3.y * w1.w;
    }
    out[(size_t)m * K_ + kk] = acc + bout[kk];
}

// ---------------- CRF forward (faithful to reference's cross-batch sum) ----------------
__global__ __launch_bounds__(1024) void crf_k(const float* __restrict__ tag,
                                              const float* __restrict__ trans,
                                              float* __restrict__ out) {
    __shared__ float albuf[2][64][17];
    const int tid = threadIdx.x;
    const int kn = tid >> 6, b = tid & 63;   // wave = next-tag, lane = batch
    float trow[16];
#pragma unroll
    for (int kp = 0; kp < 16; ++kp) trow[kp] = trans[kn * 16 + kp];
    albuf[0][b][kn] = (kn == START_) ? 0.f : NEG_;
    __syncthreads();
    int cur = 0;
    for (int t = 0; t < T_; ++t) {
        const float feat = tag[(size_t)(b * T_ + t) * K_ + kn];
        float v[16];
        float m = -3.4e38f;
#pragma unroll
        for (int kp = 0; kp < 16; ++kp) {
            v[kp] = albuf[cur][b][kp] + trow[kp];
            m = fmaxf(m, v[kp]);
        }
        float sm = 0.f;
#pragma unroll
        for (int kp = 0; kp < 16; ++kp) sm += __expf(v[kp] - m);
#pragma unroll
        for (int off = 32; off >= 1; off >>= 1) sm += __shfl_xor(sm, off, 64);
        albuf[cur ^ 1][b][kn] = feat + m + __logf(sm);
        __syncthreads();
        cur ^= 1;
    }
    const float term = albuf[cur][b][kn] + trans[STOP_ * 16 + kn];
    albuf[cur ^ 1][b][kn] = term;
    __syncthreads();
    if (tid < 64) {   // all in wave 0
        float mb = -3.4e38f;
#pragma unroll
        for (int k2 = 0; k2 < 16; ++k2) mb = fmaxf(mb, albuf[cur ^ 1][tid][k2]);
        float p = 0.f;
#pragma unroll
        for (int k2 = 0; k2 < 16; ++k2) p += __expf(albuf[cur ^ 1][tid][k2] - mb);
#pragma unroll
        for (int off = 32; off >= 1; off >>= 1) p += __shfl_xor(p, off, 64);
        out[(size_t)B_ * T_ * K_ + tid] = mb + __logf(p);
    }
}

extern "C" void kernel_launch(void* const* d_in, const int* in_sizes, int n_in,
                              void* d_out, int out_size, void* d_ws, size_t ws_size,
                              hipStream_t stream) {
    const int*   x     = (const int*)d_in[0];
    const float* emb   = (const float*)d_in[2];
    const float* w_ih  = (const float*)d_in[3];
    const float* w_hh  = (const float*)d_in[4];
    const float* b_ih  = (const float*)d_in[5];
    const float* b_hh  = (const float*)d_in[6];
    const float* h0    = (const float*)d_in[7];
    const float* c0    = (const float*)d_in[8];
    const float* w_out = (const float*)d_in[9];
    const float* b_out = (const float*)d_in[10];
    const float* trans = (const float*)d_in[11];
    float* out = (float*)d_out;

    // workspace layout (≈199 MB)
    char* ws = (char*)d_ws;
    u32*      wq    = (u32*)ws;                                   // 1 MB   [L][2][1024][64] i8-packed
    float*    dqw   = (float*)(ws + ((size_t)1 << 20));           // 16 KB  [L][2][1024]
    _Float16* wih16 = (_Float16*)(ws + ((size_t)2 << 20));        // 4 MB   [L][2048][512]
    float*    bsum  = (float*)(ws + ((size_t)6 << 20));           // 16 KB  [L][2048]
    _Float16* xe    = (_Float16*)(ws + ((size_t)7 << 20));        // 32 MB  [32768][512] (reused as H1)
    _Float16* Zb    = (_Float16*)(ws + ((size_t)39 << 20));       // 128 MB [32768][2048]
    _Float16* H0b   = (_Float16*)(ws + ((size_t)167 << 20));      // 32 MB  [32768][512]
    if (ws_size < ((size_t)199 << 20)) return;

    quant_whh_k<<<4096, 64, 0, stream>>>(w_hh, wq, dqw);
    cvt_f16_k<<<2048, 256, 0, stream>>>(w_ih, wih16, 2097152 / 4);
    bias_sum_k<<<16, 256, 0, stream>>>(b_ih, b_hh, bsum);
    embed_k<<<B_ * T_, 128, 0, stream>>>(x, emb, xe);

    // layer 0
    gemm_bt<<<(32768 / 128) * (2048 / 128), 256, 0, stream>>>(xe, wih16, bsum, Zb, 32768, 2048, 512);
    lstm_layer_k<<<128, 512, 0, stream>>>(wq, dqw, h0, c0, Zb, H0b);
    // layer 1
    gemm_bt<<<(32768 / 128) * (2048 / 128), 256, 0, stream>>>(H0b, wih16 + (size_t)2048 * 512, bsum + 2048, Zb, 32768, 2048, 512);
    lstm_layer_k<<<128, 512, 0, stream>>>(wq + (size_t)2048 * 64, dqw + 2048,
                                          h0 + 2 * B_ * HD_, c0 + 2 * B_ * HD_, Zb, xe /*H1*/);
    // emissions + CRF
    tag_k<<<32768 / 16, 256, 0, stream>>>(xe, w_out, b_out, out);
    crf_k<<<1, 1024, 0, stream>>>(out, trans, out);
}